// Round 1
// baseline (208.446 us; speedup 1.0000x reference)
//
#include <hip/hip_runtime.h>

// CTC loss forward DP (Keras ctc_batch_cost semantics), mean over batch.
// B=512 examples, T=512 timesteps, C=96 classes (blank=95), L=64 max labels.
// One wave (64 lanes) per example: lane i owns extended states 2i (blank) and
// 2i+1 (label i); lane 63 also owns state 128 (final blank). Whole DP in log2
// space (v_exp_f32/v_log_f32 are native exp2/log2); convert to ln at the end.

#define B_ 512
#define T_ 512
#define C_ 96
#define L_ 64
#define BLANK_ 95
#define NEGF (-1e30f)
#define EPSF 1e-7f
#define LN2F 0.69314718055994530942f

__device__ __forceinline__ float fexp2(float x) {
#if __has_builtin(__builtin_amdgcn_exp2f)
    return __builtin_amdgcn_exp2f(x);
#else
    return exp2f(x);
#endif
}

__device__ __forceinline__ float flog2(float x) {
#if __has_builtin(__builtin_amdgcn_logf)
    return __builtin_amdgcn_logf(x);
#else
    return log2f(x);
#endif
}

// log2(2^x + 2^y)
__device__ __forceinline__ float lse2(float x, float y) {
    float m = fmaxf(x, y);
    return m + flog2(fexp2(x - m) + fexp2(y - m));
}

// log2(2^x + 2^y + 2^z)
__device__ __forceinline__ float lse3(float x, float y, float z) {
    float m = fmaxf(fmaxf(x, y), z);
    return m + flog2(fexp2(x - m) + fexp2(y - m) + fexp2(z - m));
}

__launch_bounds__(64, 1)
__global__ void ctc_loss_kernel(const int* __restrict__ y_true,
                                const float* __restrict__ y_pred,
                                float* __restrict__ out) {
    const int b = blockIdx.x;
    const int lane = threadIdx.x;  // 0..63

    // ---- labels / extended-label metadata (all in registers) ----
    const int yv = y_true[b * L_ + lane];
    const unsigned long long act = __ballot(yv != -1);
    const int len = __popcll(act);          // label length, in [32, 64]
    const int lab = (yv == -1) ? 0 : yv;    // padded positions -> class 0 (harmless: states > 2*len never feed states <= 2*len)
    const int lab_prev = __shfl_up(lab, 1);
    const bool cs = (lane == 0) ? true : (lab != lab_prev);  // can_skip for odd state 2*lane+1
    const bool need128 = (len == L_);       // state 128 only read when len == 64

    const float* rowp = y_pred + (size_t)b * T_ * C_;

    // ---- emission prefetch: 8-step chunks, double buffered ----
    constexpr int U = 8;
    float rl[U], rb[U], nl[U], nb[U];
#pragma unroll
    for (int k = 0; k < U; ++k) {
        rl[k] = rowp[k * C_ + lab];     // my label's prob at time k
        rb[k] = rowp[k * C_ + BLANK_];  // blank prob at time k (broadcast addr)
    }

    // ---- alpha init (t = 0): only states 0 and 1 live ----
    float a_even, a_odd;
    float a128 = NEGF;
    {
        const float eb0 = flog2(rb[0] + EPSF);
        const float el0 = flog2(rl[0] + EPSF);
        a_even = (lane == 0) ? eb0 : NEGF;  // state 0 = blank
        a_odd  = (lane == 0) ? el0 : NEGF;  // state 1 = label 0
    }

    // One DP step given raw probs (label, blank) at this timestep.
    auto step = [&](float rlk, float rbk) {
        const float eb = flog2(rbk + EPSF);  // off the serial chain
        const float el = flog2(rlk + EPSF);
        float po = __shfl_up(a_odd, 1);      // alpha[2*lane - 1]
        po = (lane == 0) ? NEGF : po;
        // even state 2i: blank, no skip -> 2-way
        const float ne = lse2(a_even, po) + eb;
        // odd state 2i+1: self, own even (old), skip from prev odd if cs
        const float no = lse3(a_odd, a_even, cs ? po : NEGF) + el;
        // state 128 (lane 63's own odd/even feed it); uniform branch per wave
        if (need128) a128 = lse2(a128, a_odd) + eb;
        a_even = ne;
        a_odd = no;
    };

    // ---- chunk 0: prefetch chunk 1, run steps t = 1..7 ----
    {
#pragma unroll
        for (int k = 0; k < U; ++k) {
            nl[k] = rowp[(U + k) * C_ + lab];
            nb[k] = rowp[(U + k) * C_ + BLANK_];
        }
#pragma unroll
        for (int k = 1; k < U; ++k) step(rl[k], rb[k]);
#pragma unroll
        for (int k = 0; k < U; ++k) { rl[k] = nl[k]; rb[k] = nb[k]; }
    }

    // ---- remaining chunks ----
    for (int t0 = U; t0 < T_; t0 += U) {
        const int t1 = t0 + U;
        if (t1 < T_) {
#pragma unroll
            for (int k = 0; k < U; ++k) {
                nl[k] = rowp[(t1 + k) * C_ + lab];
                nb[k] = rowp[(t1 + k) * C_ + BLANK_];
            }
        }
#pragma unroll
        for (int k = 0; k < U; ++k) step(rl[k], rb[k]);
        if (t1 < T_) {
#pragma unroll
            for (int k = 0; k < U; ++k) { rl[k] = nl[k]; rb[k] = nb[k]; }
        }
    }

    // ---- readout: -ln2 * log2addexp2(alpha[2*len], alpha[2*len-1]) ----
    const float al = __shfl(a_odd, len - 1);            // state 2*len-1 (odd of lane len-1)
    const float ab_lt = __shfl(a_even, (len < L_) ? len : 0);
    const float ab_ge = __shfl(a128, 63);               // state 128 when len == 64
    const float ab = (len < L_) ? ab_lt : ab_ge;

    if (lane == 0) {
        const float m = fmaxf(ab, al);
        const float loss = -LN2F * (m + flog2(fexp2(ab - m) + fexp2(al - m)));
        atomicAdd(out, loss * (1.0f / B_));
    }
}

extern "C" void kernel_launch(void* const* d_in, const int* in_sizes, int n_in,
                              void* d_out, int out_size, void* d_ws, size_t ws_size,
                              hipStream_t stream) {
    const int* y_true = (const int*)d_in[0];
    const float* y_pred = (const float*)d_in[1];
    float* out = (float*)d_out;
    // d_out is poisoned before every timed launch; we accumulate into it.
    hipMemsetAsync(out, 0, sizeof(float), stream);
    ctc_loss_kernel<<<B_, 64, 0, stream>>>(y_true, y_pred, out);
}

// Round 2
// 155.605 us; speedup vs baseline: 1.3396x; 1.3396x over previous
//
#include <hip/hip_runtime.h>

// CTC loss forward DP (Keras ctc_batch_cost), mean over batch.
// B=512, T=512, C=96 (blank=95), L=64. One wave per example; lane i owns
// extended states 2i (blank) and 2i+1 (label i); lane 63 also owns state 128.
//
// R2: DP runs in LINEAR probability space (recurrence is linear), with
// wave-uniform renormalization every 8 steps (DPP wave-max -> ldexp to 2^96,
// exponent tracked in an int). Neighbor-state transfer uses DPP wave_shr:1
// (VALU latency) instead of ds_permute (~120 cy). Emissions prefetched in a
// 3-deep ring of 8-step chunks.

#define B_ 512
#define T_ 512
#define C_ 96
#define L_ 64
#define BLANK_ 95
#define EPSF 1e-7f
#define LN2F 0.69314718055994530942f

template <int CTRL>
__device__ __forceinline__ float dpp_mov(float x) {
    // bound_ctrl=true: invalid source lanes read 0 (identity for max of probs,
    // and exactly the "state -1 doesn't exist" boundary for wave_shr:1).
    return __int_as_float(
        __builtin_amdgcn_update_dpp(0, __float_as_int(x), CTRL, 0xF, 0xF, true));
}

// Full-wave max (64 lanes), all-VALU. Result returned wave-uniform (SGPR).
__device__ __forceinline__ float wave_max(float m) {
    m = fmaxf(m, dpp_mov<0x111>(m));  // row_shr:1
    m = fmaxf(m, dpp_mov<0x112>(m));  // row_shr:2
    m = fmaxf(m, dpp_mov<0x114>(m));  // row_shr:4
    m = fmaxf(m, dpp_mov<0x118>(m));  // row_shr:8   -> lane 15+16k = row max
    m = fmaxf(m, dpp_mov<0x142>(m));  // row_bcast:15
    m = fmaxf(m, dpp_mov<0x143>(m));  // row_bcast:31 -> lane 63 = wave max
    return __int_as_float(__builtin_amdgcn_readlane(__float_as_int(m), 63));
}

__launch_bounds__(64, 1)
__global__ void ctc_loss_kernel(const int* __restrict__ y_true,
                                const float* __restrict__ y_pred,
                                float* __restrict__ out) {
    const int b = blockIdx.x;
    const int lane = threadIdx.x;  // 0..63

    // ---- label metadata ----
    const int yv = y_true[b * L_ + lane];
    const unsigned long long act = __ballot(yv != -1);
    const int len = __popcll(act);        // label length (32..64)
    const int lab = (yv == -1) ? 0 : yv;  // padded like the reference
    const int lab_prev = __shfl_up(lab, 1);
    const bool cs = (lane == 0) ? true : (lab != lab_prev);

    const float* rowp = y_pred + (size_t)b * T_ * C_;
    const float* plp = rowp + lab;     // my label's column
    const float* pbp = rowp + BLANK_;  // blank column

    // ---- emission prefetch ring: 3 chunks x 8 steps ----
    constexpr int U = 8;
    constexpr int NCH = T_ / U;  // 64
    float bl[3][U], bb[3][U];
#pragma unroll
    for (int d = 0; d < 3; ++d)
#pragma unroll
        for (int k = 0; k < U; ++k) {
            bl[d][k] = plp[(d * U + k) * C_];
            bb[d][k] = pbp[(d * U + k) * C_];
        }

    // ---- state (linear space, scaled by 2^-accum) ----
    float a_even, a_odd, a128;
    int accum = 0;  // true_alpha = stored * 2^accum
    {
        const float pb0 = bb[0][0] + EPSF;
        const float pl0 = bl[0][0] + EPSF;
        a_even = (lane == 0) ? pb0 : 0.0f;  // state 0
        a_odd  = (lane == 0) ? pl0 : 0.0f;  // state 1
        a128 = 0.0f;                        // state 128
    }

    auto step = [&](float rl, float rb) {
        const float pbv = rb + EPSF;
        const float plv = rl + EPSF;
        const float po = dpp_mov<0x138>(a_odd);  // wave_shr:1 -> alpha[2*lane-1]
        const float pos = cs ? po : 0.0f;
        const float ne = (a_even + po) * pbv;
        const float no = (a_odd + a_even + pos) * plv;
        a128 = (a128 + a_odd) * pbv;  // meaningful on lane 63 only; harmless elsewhere
        a_even = ne;
        a_odd = no;
    };

    auto renorm = [&]() {
        const float mv = wave_max(fmaxf(fmaxf(a_even, a_odd), a128));
        // mv = 1.f * 2^(E-127) < 2^(E-126); bring max up to ~2^96.
        const int e = ((__float_as_int(mv) >> 23) & 0xFF) - 126;
        const int k = 96 - e;
        a_even = ldexpf(a_even, k);
        a_odd  = ldexpf(a_odd, k);
        a128   = ldexpf(a128, k);
        accum -= k;
    };

    auto prefetch = [&](float* dl, float* db, int t0) {
#pragma unroll
        for (int k = 0; k < U; ++k) {
            dl[k] = plp[(t0 + k) * C_];
            db[k] = pbp[(t0 + k) * C_];
        }
    };

    // ---- chunk 0: steps 1..7, then renorm, refill slot 0 with chunk 3 ----
#pragma unroll
    for (int k = 1; k < U; ++k) step(bl[0][k], bb[0][k]);
    renorm();
    prefetch(bl[0], bb[0], 3 * U);

    // ---- chunks 1..63 in groups of 3 (slots 1,2,0) ----
    for (int g = 0; g < 21; ++g) {
        const int cbase = 1 + g * 3;
#pragma unroll
        for (int sub = 0; sub < 3; ++sub) {
            const int slot = (sub + 1) % 3;  // c = cbase+sub -> slot (c%3)
#pragma unroll
            for (int k = 0; k < U; ++k) step(bl[slot][k], bb[slot][k]);
            renorm();
            const int pc = cbase + sub + 3;  // chunk to prefetch into this slot
            if (pc < NCH) prefetch(bl[slot], bb[slot], pc * U);
        }
    }

    // ---- readout: loss = -ln2 * (log2(a[2len] + a[2len-1]) + accum) ----
    const float al = __shfl(a_odd, len - 1);                 // state 2len-1
    const float ab = (len < L_) ? __shfl(a_even, len)        // state 2len
                                : __shfl(a128, 63);          // state 128
    if (lane == 0) {
        const float loss = -LN2F * (log2f(ab + al) + (float)accum);
        atomicAdd(out, loss * (1.0f / B_));
    }
}

extern "C" void kernel_launch(void* const* d_in, const int* in_sizes, int n_in,
                              void* d_out, int out_size, void* d_ws, size_t ws_size,
                              hipStream_t stream) {
    const int* y_true = (const int*)d_in[0];
    const float* y_pred = (const float*)d_in[1];
    float* out = (float*)d_out;
    hipMemsetAsync(out, 0, sizeof(float), stream);
    ctc_loss_kernel<<<B_, 64, 0, stream>>>(y_true, y_pred, out);
}